// Round 11
// baseline (181.751 us; speedup 1.0000x reference)
//
#include <hip/hip_runtime.h>
#include <math.h>

#define D128 128
#define SCAPW 256   // per-wave LDS score capacity (deg ~ Poisson(32); P(deg>256)~0)

typedef unsigned int uint32;
typedef unsigned short ushort_t;
typedef short bf16x8 __attribute__((ext_vector_type(8)));
typedef float f32x4 __attribute__((ext_vector_type(4)));
typedef float f32x2 __attribute__((ext_vector_type(2)));

// fp32 -> bf16 (RNE)
__device__ __forceinline__ ushort_t bf16_of(float x) {
  uint32 u = __float_as_uint(x);
  return (ushort_t)((u + 0x7fffu + ((u >> 16) & 1u)) >> 16);
}
__device__ __forceinline__ uint32 pack_bf2(float x, float y) {
  uint32 bx = __float_as_uint(x);
  uint32 by = __float_as_uint(y);
  bx = (bx + 0x7fffu + ((bx >> 16) & 1u)) >> 16;
  by = (by + 0x7fffu + ((by >> 16) & 1u)) & 0xffff0000u;
  return bx | by;
}
__device__ __forceinline__ float bf_lo(uint32 u) { return __uint_as_float(u << 16); }
__device__ __forceinline__ float bf_hi(uint32 u) { return __uint_as_float(u & 0xffff0000u); }

// tanh(x) = 1 - 2/(1+exp(2x)) via v_exp + v_rcp
__device__ __forceinline__ float fast_tanh(float x) {
  float e = __expf(2.0f * x);
  float r = __builtin_amdgcn_rcpf(1.0f + e);
  return fmaf(-2.0f, r, 1.0f);
}

// pack 4 fp32 -> 4 OCP e4m3 fp8 in one uint (HW RNE)
__device__ __forceinline__ uint32 pack_fp8x4(float a, float b, float c, float d) {
  int u = __builtin_amdgcn_cvt_pk_fp8_f32(a, b, 0, false);
  u = __builtin_amdgcn_cvt_pk_fp8_f32(c, d, u, true);
  return (uint32)u;
}

// ---------------------------------------------------------------------------
// prep_all: one dispatch, block-range partitioned:
//   [0, nb_conv)   : fp32 -> bf16 of h_src, s_emb, h_dst; fp32 -> fp8 of h_src
//   [nb_conv,+16)  : W1 -> MFMA A/B-fragment-ordered bf16 Wfrag (2 halves)
//   [+16,+16)      : Wo -> fragment-ordered bf16 Wo_frag (K=256)
//   [+32, ...)     : segment offsets from sorted dst_idx
// ---------------------------------------------------------------------------
__global__ __launch_bounds__(256) void prep_all(
    const float* __restrict__ h_src, const float* __restrict__ s_emb,
    const float* __restrict__ h_dst,
    const float* __restrict__ W1, const float* __restrict__ Wo,
    const int* __restrict__ dst_idx,
    uint32* __restrict__ h_src_bf, uint32* __restrict__ s_emb_bf,
    uint32* __restrict__ h_dst_bf, uint32* __restrict__ h_src_f8,
    ushort_t* __restrict__ Wfrag, ushort_t* __restrict__ Wo_frag,
    int* __restrict__ off,
    int n_src_el, int n_dst_el, int E, int N, int nb_conv) {
  const int b = blockIdx.x;
  const int tid = threadIdx.x;
  if (b < nb_conv) {
    int i = (b * 256 + tid) * 8;
    const int n_bf_el = n_src_el + 2 * n_dst_el;
    if (i < n_bf_el) {
      const float* src;
      uint32* dst;
      if (i < n_src_el) { src = h_src + i; dst = h_src_bf + (i >> 1); }
      else if (i < n_src_el + n_dst_el) {
        src = s_emb + (i - n_src_el); dst = s_emb_bf + ((i - n_src_el) >> 1);
      } else {
        src = h_dst + (i - n_src_el - n_dst_el);
        dst = h_dst_bf + ((i - n_src_el - n_dst_el) >> 1);
      }
      float4 a = *(const float4*)src;
      float4 c = *(const float4*)(src + 4);
      uint4 p;
      p.x = pack_bf2(a.x, a.y);
      p.y = pack_bf2(a.z, a.w);
      p.z = pack_bf2(c.x, c.y);
      p.w = pack_bf2(c.z, c.w);
      *(uint4*)dst = p;
    } else {
      int k = i - n_bf_el;
      if (k >= n_src_el) return;
      float4 a = *(const float4*)(h_src + k);
      float4 c = *(const float4*)(h_src + k + 4);
      uint2 p;
      p.x = pack_fp8x4(a.x, a.y, a.z, a.w);
      p.y = pack_fp8x4(c.x, c.y, c.z, c.w);
      *(uint2*)(h_src_f8 + (k >> 2)) = p;
    }
  } else if (b < nb_conv + 16) {
    // W1 fragments: t indexes [h][nt][kc][lane]; frag[j]=W1[k][n] (k=quad*8+j)
    int t = (b - nb_conv) * 256 + tid;   // 0..4095
    int lane = t & 63;
    int kc = (t >> 6) & 3;
    int nt = (t >> 8) & 7;
    int h = (t >> 11) & 1;
    int m = lane & 15;
    int quad = lane >> 4;
    int krow = h * D128 + kc * 32 + quad * 8;
    int ncol = nt * 16 + m;
    ushort_t fr[8];
#pragma unroll
    for (int j = 0; j < 8; j++) fr[j] = bf16_of(W1[(size_t)(krow + j) * D128 + ncol]);
    *(uint4*)(Wfrag + (size_t)t * 8) = *(const uint4*)fr;
  } else if (b < nb_conv + 32) {
    // Wo fragments: t indexes [nt][kc8][lane], kc8 0..7 (K=256)
    int t = (b - nb_conv - 16) * 256 + tid;   // 0..4095
    int lane = t & 63;
    int kc = (t >> 6) & 7;
    int nt = (t >> 9) & 7;
    int m = lane & 15;
    int quad = lane >> 4;
    int krow = kc * 32 + quad * 8;
    int ncol = nt * 16 + m;
    ushort_t fr[8];
#pragma unroll
    for (int j = 0; j < 8; j++) fr[j] = bf16_of(Wo[(size_t)(krow + j) * D128 + ncol]);
    *(uint4*)(Wo_frag + (size_t)t * 8) = *(const uint4*)fr;
  } else {
    int e = (b - nb_conv - 32) * 256 + tid;
    if (e >= E) return;
    int d = dst_idx[e];
    int dprev = (e == 0) ? -1 : dst_idx[e - 1];
    for (int v = dprev + 1; v <= d; v++) off[v] = e;
    if (e == E - 1) {
      for (int v = d + 1; v <= N; v++) off[v] = E;
    }
  }
}

// ---------------------------------------------------------------------------
// Merged GEMM, fp8 output: P_f8 = (X @ W) for two problems in one dispatch.
// Operand-SWAPPED MFMA: A = Wfrag (channels as M-rows), B = X-row fragments
// (identical loads as before). D: col=lane&15 -> X-row, row=quad*4+r ->
// 4 CONSECUTIVE channels per lane -> in-lane cvt_pk_fp8 pack.
// Epilogue: LDS repack -> coalesced 128-B-row stores.
// ---------------------------------------------------------------------------
__global__ __launch_bounds__(256) void gemm_mfma(
    const ushort_t* __restrict__ Xa, const ushort_t* __restrict__ Xb,
    const ushort_t* __restrict__ Wfrag,
    uint32* __restrict__ Pa, uint32* __restrict__ Pb,
    int Ma, int Mb, int nblk_a) {
  __shared__ uint32 Ys8[128][36];   // 18 KB; stride 144 B (16-B aligned)
  const int blk = blockIdx.x;
  const ushort_t* X;
  const bf16x8* Wf;
  uint32* P;
  int M, row0;
  if (blk < nblk_a) { X = Xa; P = Pa; Wf = (const bf16x8*)Wfrag;           M = Ma; row0 = blk * 128; }
  else              { X = Xb; P = Pb; Wf = (const bf16x8*)(Wfrag + 16384); M = Mb; row0 = (blk - nblk_a) * 128; }

  const int tid = threadIdx.x;
  const int wave = tid >> 6;
  const int lane = tid & 63;
  const int m = lane & 15;
  const int quad = lane >> 4;

  const int ra0 = min(row0 + wave * 32 + m, M - 1);
  const int ra1 = min(row0 + wave * 32 + 16 + m, M - 1);

  f32x4 acc[2][8];
#pragma unroll
  for (int st = 0; st < 2; st++)
#pragma unroll
    for (int nt = 0; nt < 8; nt++) acc[st][nt] = (f32x4){0.f, 0.f, 0.f, 0.f};

#pragma unroll
  for (int kc = 0; kc < 4; kc++) {
    bf16x8 x0 = *(const bf16x8*)(X + (size_t)ra0 * D128 + kc * 32 + quad * 8);
    bf16x8 x1 = *(const bf16x8*)(X + (size_t)ra1 * D128 + kc * 32 + quad * 8);
#pragma unroll
    for (int nt = 0; nt < 8; nt++) {
      bf16x8 wf = Wf[(nt * 4 + kc) * 64 + lane];
      acc[0][nt] = __builtin_amdgcn_mfma_f32_16x16x32_bf16(wf, x0, acc[0][nt], 0, 0, 0);
      acc[1][nt] = __builtin_amdgcn_mfma_f32_16x16x32_bf16(wf, x1, acc[1][nt], 0, 0, 0);
    }
  }

  // lane holds channels nt*16+quad*4..+3 for X-row wave*32+st*16+m
#pragma unroll
  for (int st = 0; st < 2; st++)
#pragma unroll
    for (int nt = 0; nt < 8; nt++)
      Ys8[wave * 32 + st * 16 + m][nt * 4 + quad] =
          pack_fp8x4(acc[st][nt][0], acc[st][nt][1], acc[st][nt][2], acc[st][nt][3]);
  __syncthreads();

  // coalesced store: 128 rows x 32 uints (128 B/row), 16 B/thread/iter
#pragma unroll
  for (int it = 0; it < 4; it++) {
    int f = tid + 256 * it;        // 0..1023
    int row = f >> 3;
    int cu = (f & 7) * 4;
    int grow = row0 + row;
    if (grow < M) *(uint4*)(P + (size_t)grow * 32 + cu) = *(const uint4*)(&Ys8[row][cu]);
  }
}

// ---------------------------------------------------------------------------
// Fused attention + aggregation, WAVE-PER-DST, SINGLE PASS over edges:
// per edge: gather p_src_f8 row (score) AND h_src_f8 row (aggregate with
// un-normalized ex); divide by den at the end. No barriers at all.
// fp8 tables halve gather bytes vs bf16.
// ---------------------------------------------------------------------------
__global__ __launch_bounds__(256) void attn_agg_kernel(
    const uint32* __restrict__ p_src_f8, const uint32* __restrict__ p_dst_f8,
    const float* __restrict__ w2, const float* __restrict__ ew,
    const int* __restrict__ src_idx, const int* __restrict__ off,
    const uint32* __restrict__ h_src_f8,
    float* __restrict__ attn_out, uint32* __restrict__ h_glob_bf, int N_dst) {
  const int tid = threadIdx.x;
  const int wv = tid >> 6;
  const int lane = tid & 63;
  const int v = blockIdx.x * 4 + wv;

  __shared__ float sex[4][SCAPW];
  if (v >= N_dst) return;

  const int lo = off[v], hi = off[v + 1];
  const int deg = hi - lo;
  const int sub = lane & 15;   // lane covers channels sub*8..+7
  const int eg = lane >> 4;    // edge slot 0..3 within wave
  const bool fast = (deg <= SCAPW);

  // per-lane w2 segment + decoded p_dst segment (row wave-uniform, L1-hot)
  float4 wA = *(const float4*)(w2 + sub * 8);
  float4 wB = *(const float4*)(w2 + sub * 8 + 4);
  uint2 pdu = *(const uint2*)(p_dst_f8 + (size_t)v * 32 + sub * 2);
  f32x2 pd0 = __builtin_amdgcn_cvt_pk_f32_fp8(pdu.x, false);
  f32x2 pd1 = __builtin_amdgcn_cvt_pk_f32_fp8(pdu.x, true);
  f32x2 pd2 = __builtin_amdgcn_cvt_pk_f32_fp8(pdu.y, false);
  f32x2 pd3 = __builtin_amdgcn_cvt_pk_f32_fp8(pdu.y, true);

  float den = 0.f;
  float acc[8];
#pragma unroll
  for (int j = 0; j < 8; j++) acc[j] = 0.f;

  for (int base = 0; base < deg; base += 4) {
    const int ei = base + eg;
    float ex = 0.f;
    if (ei < deg) {
      const int e = lo + ei;
      const int s = src_idx[e];
      const float ewv = ew[e];
      uint2 us = *(const uint2*)(p_src_f8 + (size_t)s * 32 + sub * 2);
      f32x2 a0 = __builtin_amdgcn_cvt_pk_f32_fp8(us.x, false);
      f32x2 a1 = __builtin_amdgcn_cvt_pk_f32_fp8(us.x, true);
      f32x2 a2 = __builtin_amdgcn_cvt_pk_f32_fp8(us.y, false);
      f32x2 a3 = __builtin_amdgcn_cvt_pk_f32_fp8(us.y, true);
      float sc;
      sc = fast_tanh(a0.x + pd0.x) * wA.x;
      sc = fmaf(fast_tanh(a0.y + pd0.y), wA.y, sc);
      sc = fmaf(fast_tanh(a1.x + pd1.x), wA.z, sc);
      sc = fmaf(fast_tanh(a1.y + pd1.y), wA.w, sc);
      sc = fmaf(fast_tanh(a2.x + pd2.x), wB.x, sc);
      sc = fmaf(fast_tanh(a2.y + pd2.y), wB.y, sc);
      sc = fmaf(fast_tanh(a3.x + pd3.x), wB.z, sc);
      sc = fmaf(fast_tanh(a3.y + pd3.y), wB.w, sc);
#pragma unroll
      for (int o = 1; o <= 8; o <<= 1) sc += __shfl_xor(sc, o, 64);
      ex = __expf(sc * ewv);
      if (sub == 0) {
        if (fast) sex[wv][ei] = ex;
        else attn_out[lo + ei] = ex;   // staged un-normalized
      }
      // fused aggregation gather (same index s)
      uint2 uh = *(const uint2*)(h_src_f8 + (size_t)s * 32 + sub * 2);
      f32x2 h0 = __builtin_amdgcn_cvt_pk_f32_fp8(uh.x, false);
      f32x2 h1 = __builtin_amdgcn_cvt_pk_f32_fp8(uh.x, true);
      f32x2 h2 = __builtin_amdgcn_cvt_pk_f32_fp8(uh.y, false);
      f32x2 h3 = __builtin_amdgcn_cvt_pk_f32_fp8(uh.y, true);
      acc[0] = fmaf(ex, h0.x, acc[0]);
      acc[1] = fmaf(ex, h0.y, acc[1]);
      acc[2] = fmaf(ex, h1.x, acc[2]);
      acc[3] = fmaf(ex, h1.y, acc[3]);
      acc[4] = fmaf(ex, h2.x, acc[4]);
      acc[5] = fmaf(ex, h2.y, acc[5]);
      acc[6] = fmaf(ex, h3.x, acc[6]);
      acc[7] = fmaf(ex, h3.y, acc[7]);
    }
    den += (sub == 0) ? ex : 0.f;
  }

  // wave-reduce den (only sub==0 lanes contributed)
#pragma unroll
  for (int o = 1; o <= 32; o <<= 1) den += __shfl_xor(den, o, 64);
  const float inv = (deg > 0) ? 1.0f / den : 0.0f;

  // normalized attn store (contiguous)
  if (fast) {
    for (int i = lane; i < deg; i += 64) attn_out[lo + i] = sex[wv][i] * inv;
  } else {
    for (int i = lane; i < deg; i += 64) attn_out[lo + i] *= inv;
  }

  // cross-edge-group reduce (lanes differ in bits 4-5)
#pragma unroll
  for (int j = 0; j < 8; j++) {
    acc[j] += __shfl_xor(acc[j], 16, 64);
    acc[j] += __shfl_xor(acc[j], 32, 64);
  }
  if (eg == 0) {   // lanes 0..15 hold final channels sub*8..+7
    uint4 o;
    o.x = pack_bf2(acc[0] * inv, acc[1] * inv);
    o.y = pack_bf2(acc[2] * inv, acc[3] * inv);
    o.z = pack_bf2(acc[4] * inv, acc[5] * inv);
    o.w = pack_bf2(acc[6] * inv, acc[7] * inv);
    *(uint4*)(h_glob_bf + (size_t)v * 64 + sub * 4) = o;
  }
}

// ---------------------------------------------------------------------------
// MFMA output projection + fused LayerNorm.
// out = [h_dst|h_glob](bf16) @ Wo_frag + bo; x = h_dst(f32) + out; y = LN(x).
// 128 threads = 2 waves x 16 rows -> 32 rows/block.
// ---------------------------------------------------------------------------
__global__ __launch_bounds__(128) void out_mfma_ln(
    const ushort_t* __restrict__ h_dst_bf, const ushort_t* __restrict__ h_glob_bf,
    const ushort_t* __restrict__ Wo_frag,
    const float* __restrict__ h_dst, const float* __restrict__ bo,
    const float* __restrict__ gamma, const float* __restrict__ beta,
    float* __restrict__ y, int N) {
  __shared__ float sbo[128], sgam[128], sbet[128];
  const int tid = threadIdx.x;
  if (tid < 128) { sbo[tid] = bo[tid]; sgam[tid] = gamma[tid]; sbet[tid] = beta[tid]; }
  __syncthreads();

  const int w = tid >> 6;
  const int lane = tid & 63;
  const int m = lane & 15;
  const int quad = lane >> 4;
  const int row0 = blockIdx.x * 32 + w * 16;
  const int ra = min(row0 + m, N - 1);
  const bf16x8* Wf = (const bf16x8*)Wo_frag;

  f32x4 acc[8];
#pragma unroll
  for (int nt = 0; nt < 8; nt++) acc[nt] = (f32x4){0.f, 0.f, 0.f, 0.f};

#pragma unroll
  for (int kc = 0; kc < 8; kc++) {
    const ushort_t* X = (kc < 4) ? h_dst_bf : h_glob_bf;
    const int kk = kc & 3;
    bf16x8 a = *(const bf16x8*)(X + (size_t)ra * D128 + kk * 32 + quad * 8);
#pragma unroll
    for (int nt = 0; nt < 8; nt++) {
      bf16x8 bfr = Wf[(nt * 8 + kc) * 64 + lane];
      acc[nt] = __builtin_amdgcn_mfma_f32_16x16x32_bf16(a, bfr, acc[nt], 0, 0, 0);
    }
  }

#pragma unroll
  for (int r = 0; r < 4; r++) {
    const int grow = row0 + quad * 4 + r;
    const int gr = min(grow, N - 1);
    float x[8];
    float s1 = 0.f, s2 = 0.f;
#pragma unroll
    for (int nt = 0; nt < 8; nt++) {
      float hd = h_dst[(size_t)gr * D128 + nt * 16 + m];
      float xv = hd + acc[nt][r] + sbo[nt * 16 + m];
      x[nt] = xv;
      s1 += xv;
      s2 = fmaf(xv, xv, s2);
    }
#pragma unroll
    for (int o = 1; o <= 8; o <<= 1) {
      s1 += __shfl_xor(s1, o, 64);
      s2 += __shfl_xor(s2, o, 64);
    }
    float mu = s1 * (1.0f / 128.0f);
    float var = s2 * (1.0f / 128.0f) - mu * mu;
    float rstd = __builtin_amdgcn_rcpf(sqrtf(var + 1e-5f));
    if (grow < N) {
#pragma unroll
      for (int nt = 0; nt < 8; nt++) {
        int c = nt * 16 + m;
        y[(size_t)grow * D128 + c] = (x[nt] - mu) * rstd * sgam[c] + sbet[c];
      }
    }
  }
}

extern "C" void kernel_launch(void* const* d_in, const int* in_sizes, int n_in,
                              void* d_out, int out_size, void* d_ws, size_t ws_size,
                              hipStream_t stream) {
  const float* h_src = (const float*)d_in[0];
  const float* h_dst = (const float*)d_in[1];
  const float* s_emb = (const float*)d_in[2];
  const float* ew    = (const float*)d_in[3];
  const int* src_idx = (const int*)d_in[4];
  const int* dst_idx = (const int*)d_in[5];
  const float* W1    = (const float*)d_in[6];
  const float* w2    = (const float*)d_in[7];
  const float* Wo    = (const float*)d_in[8];
  const float* bo    = (const float*)d_in[9];
  const float* gamma = (const float*)d_in[10];
  const float* beta  = (const float*)d_in[11];

  const int N_src = in_sizes[0] / D128;
  const int N_dst = in_sizes[1] / D128;
  const int E = in_sizes[3];

  float* out_y = (float*)d_out;                       // [N_dst*128]
  float* out_attn = out_y + (size_t)N_dst * D128;     // [E]

  // ws layout:
  uint32* p_src_f8 = (uint32*)d_ws;                            // N_src*32 (fp8 rows)
  uint32* p_dst_f8 = p_src_f8 + (size_t)N_src * 32;            // N_dst*32
  uint32* h_src_f8 = p_dst_f8 + (size_t)N_dst * 32;            // N_src*32
  uint32* h_src_bf = h_src_f8 + (size_t)N_src * 32;            // N_src*64 (bf16)
  uint32* h_dst_bf = h_src_bf + (size_t)N_src * 64;            // N_dst*64
  uint32* h_glob_bf = h_dst_bf + (size_t)N_dst * 64;           // N_dst*64
  uint32* s_emb_bf = h_glob_bf + (size_t)N_dst * 64;           // N_dst*64
  int* seg_off = (int*)(s_emb_bf + (size_t)N_dst * 64);        // N_dst+1
  ushort_t* Wfrag = (ushort_t*)(seg_off + N_dst + 1 + 3);      // 32768 shorts
  ushort_t* Wo_frag = Wfrag + 32768;                           // 32768 shorts

  const int n_src_el = N_src * D128;
  const int n_dst_el = N_dst * D128;
  const int n_conv_el = 2 * n_src_el + 2 * n_dst_el;  // bf16 of 3 arrays + fp8 of h_src
  const int nblk_a = (N_src + 127) / 128;
  const int nblk_b = (N_dst + 127) / 128;
  const int nb_conv = (n_conv_el / 8 + 255) / 256;
  const int nb_seg = (E + 255) / 256;

  prep_all<<<nb_conv + 32 + nb_seg, 256, 0, stream>>>(
      h_src, s_emb, h_dst, W1, Wo, dst_idx,
      h_src_bf, s_emb_bf, h_dst_bf, h_src_f8, Wfrag, Wo_frag, seg_off,
      n_src_el, n_dst_el, E, N_dst, nb_conv);
  gemm_mfma<<<nblk_a + nblk_b, 256, 0, stream>>>(
      (const ushort_t*)h_src_bf, (const ushort_t*)s_emb_bf, Wfrag,
      p_src_f8, p_dst_f8, N_src, N_dst, nblk_a);
  attn_agg_kernel<<<(N_dst + 3) / 4, 256, 0, stream>>>(
      p_src_f8, p_dst_f8, w2, ew, src_idx, seg_off, h_src_f8, out_attn,
      h_glob_bf, N_dst);
  out_mfma_ln<<<(N_dst + 31) / 32, 128, 0, stream>>>(
      (const ushort_t*)h_dst_bf, (const ushort_t*)h_glob_bf, Wo_frag,
      h_dst, bo, gamma, beta, out_y, N_dst);
}

// Round 12
// 173.678 us; speedup vs baseline: 1.0465x; 1.0465x over previous
//
#include <hip/hip_runtime.h>
#include <math.h>

#define D128 128
#define SCAPW 256   // per-wave LDS score capacity (deg ~ Poisson(32); P(deg>256)~0)

typedef unsigned int uint32;
typedef unsigned short ushort_t;
typedef short bf16x8 __attribute__((ext_vector_type(8)));
typedef float f32x4 __attribute__((ext_vector_type(4)));
typedef float f32x2 __attribute__((ext_vector_type(2)));

// fp32 -> bf16 (RNE)
__device__ __forceinline__ ushort_t bf16_of(float x) {
  uint32 u = __float_as_uint(x);
  return (ushort_t)((u + 0x7fffu + ((u >> 16) & 1u)) >> 16);
}
__device__ __forceinline__ uint32 pack_bf2(float x, float y) {
  uint32 bx = __float_as_uint(x);
  uint32 by = __float_as_uint(y);
  bx = (bx + 0x7fffu + ((bx >> 16) & 1u)) >> 16;
  by = (by + 0x7fffu + ((by >> 16) & 1u)) & 0xffff0000u;
  return bx | by;
}
__device__ __forceinline__ float bf_lo(uint32 u) { return __uint_as_float(u << 16); }
__device__ __forceinline__ float bf_hi(uint32 u) { return __uint_as_float(u & 0xffff0000u); }

// tanh(x) = 1 - 2/(1+exp(2x)) via v_exp + v_rcp
__device__ __forceinline__ float fast_tanh(float x) {
  float e = __expf(2.0f * x);
  float r = __builtin_amdgcn_rcpf(1.0f + e);
  return fmaf(-2.0f, r, 1.0f);
}

// pack 4 fp32 -> 4 OCP e4m3 fp8 in one uint (HW RNE)
__device__ __forceinline__ uint32 pack_fp8x4(float a, float b, float c, float d) {
  int u = __builtin_amdgcn_cvt_pk_fp8_f32(a, b, 0, false);
  u = __builtin_amdgcn_cvt_pk_fp8_f32(c, d, u, true);
  return (uint32)u;
}

// ---------------------------------------------------------------------------
// prep_all: one dispatch, block-range partitioned:
//   [0, nb_conv)   : h_src -> bf16 AND fp8 in ONE read pass; s_emb, h_dst -> bf16
//   [nb_conv,+16)  : W1 -> MFMA fragment-ordered bf16 Wfrag (2 halves)
//   [+16,+16)      : Wo -> fragment-ordered bf16 Wo_frag (K=256)
//   [+32, ...)     : segment offsets from sorted dst_idx
// ---------------------------------------------------------------------------
__global__ __launch_bounds__(256) void prep_all(
    const float* __restrict__ h_src, const float* __restrict__ s_emb,
    const float* __restrict__ h_dst,
    const float* __restrict__ W1, const float* __restrict__ Wo,
    const int* __restrict__ dst_idx,
    uint32* __restrict__ h_src_bf, uint32* __restrict__ s_emb_bf,
    uint32* __restrict__ h_dst_bf, uint32* __restrict__ h_src_f8,
    ushort_t* __restrict__ Wfrag, ushort_t* __restrict__ Wo_frag,
    int* __restrict__ off,
    int n_src_el, int n_dst_el, int E, int N, int nb_conv) {
  const int b = blockIdx.x;
  const int tid = threadIdx.x;
  if (b < nb_conv) {
    int i = (b * 256 + tid) * 8;
    if (i < n_src_el) {
      // h_src: single read -> bf16 + fp8
      float4 a = *(const float4*)(h_src + i);
      float4 c = *(const float4*)(h_src + i + 4);
      uint4 p;
      p.x = pack_bf2(a.x, a.y);
      p.y = pack_bf2(a.z, a.w);
      p.z = pack_bf2(c.x, c.y);
      p.w = pack_bf2(c.z, c.w);
      *(uint4*)(h_src_bf + (i >> 1)) = p;
      uint2 q;
      q.x = pack_fp8x4(a.x, a.y, a.z, a.w);
      q.y = pack_fp8x4(c.x, c.y, c.z, c.w);
      *(uint2*)(h_src_f8 + (i >> 2)) = q;
    } else if (i < n_src_el + 2 * n_dst_el) {
      const float* src;
      uint32* dst;
      if (i < n_src_el + n_dst_el) {
        src = s_emb + (i - n_src_el); dst = s_emb_bf + ((i - n_src_el) >> 1);
      } else {
        src = h_dst + (i - n_src_el - n_dst_el);
        dst = h_dst_bf + ((i - n_src_el - n_dst_el) >> 1);
      }
      float4 a = *(const float4*)src;
      float4 c = *(const float4*)(src + 4);
      uint4 p;
      p.x = pack_bf2(a.x, a.y);
      p.y = pack_bf2(a.z, a.w);
      p.z = pack_bf2(c.x, c.y);
      p.w = pack_bf2(c.z, c.w);
      *(uint4*)dst = p;
    }
  } else if (b < nb_conv + 16) {
    // W1 fragments: t indexes [h][nt][kc][lane]; frag[j]=W1[k][n] (k=quad*8+j)
    int t = (b - nb_conv) * 256 + tid;   // 0..4095
    int lane = t & 63;
    int kc = (t >> 6) & 3;
    int nt = (t >> 8) & 7;
    int h = (t >> 11) & 1;
    int m = lane & 15;
    int quad = lane >> 4;
    int krow = h * D128 + kc * 32 + quad * 8;
    int ncol = nt * 16 + m;
    ushort_t fr[8];
#pragma unroll
    for (int j = 0; j < 8; j++) fr[j] = bf16_of(W1[(size_t)(krow + j) * D128 + ncol]);
    *(uint4*)(Wfrag + (size_t)t * 8) = *(const uint4*)fr;
  } else if (b < nb_conv + 32) {
    // Wo fragments: t indexes [nt][kc8][lane], kc8 0..7 (K=256)
    int t = (b - nb_conv - 16) * 256 + tid;   // 0..4095
    int lane = t & 63;
    int kc = (t >> 6) & 7;
    int nt = (t >> 9) & 7;
    int m = lane & 15;
    int quad = lane >> 4;
    int krow = kc * 32 + quad * 8;
    int ncol = nt * 16 + m;
    ushort_t fr[8];
#pragma unroll
    for (int j = 0; j < 8; j++) fr[j] = bf16_of(Wo[(size_t)(krow + j) * D128 + ncol]);
    *(uint4*)(Wo_frag + (size_t)t * 8) = *(const uint4*)fr;
  } else {
    int e = (b - nb_conv - 32) * 256 + tid;
    if (e >= E) return;
    int d = dst_idx[e];
    int dprev = (e == 0) ? -1 : dst_idx[e - 1];
    for (int v = dprev + 1; v <= d; v++) off[v] = e;
    if (e == E - 1) {
      for (int v = d + 1; v <= N; v++) off[v] = E;
    }
  }
}

// ---------------------------------------------------------------------------
// Merged GEMM, fp8 output (operand-swapped MFMA; LDS repack epilogue).
// ---------------------------------------------------------------------------
__global__ __launch_bounds__(256) void gemm_mfma(
    const ushort_t* __restrict__ Xa, const ushort_t* __restrict__ Xb,
    const ushort_t* __restrict__ Wfrag,
    uint32* __restrict__ Pa, uint32* __restrict__ Pb,
    int Ma, int Mb, int nblk_a) {
  __shared__ uint32 Ys8[128][36];   // 18 KB; stride 144 B
  const int blk = blockIdx.x;
  const ushort_t* X;
  const bf16x8* Wf;
  uint32* P;
  int M, row0;
  if (blk < nblk_a) { X = Xa; P = Pa; Wf = (const bf16x8*)Wfrag;           M = Ma; row0 = blk * 128; }
  else              { X = Xb; P = Pb; Wf = (const bf16x8*)(Wfrag + 16384); M = Mb; row0 = (blk - nblk_a) * 128; }

  const int tid = threadIdx.x;
  const int wave = tid >> 6;
  const int lane = tid & 63;
  const int m = lane & 15;
  const int quad = lane >> 4;

  const int ra0 = min(row0 + wave * 32 + m, M - 1);
  const int ra1 = min(row0 + wave * 32 + 16 + m, M - 1);

  f32x4 acc[2][8];
#pragma unroll
  for (int st = 0; st < 2; st++)
#pragma unroll
    for (int nt = 0; nt < 8; nt++) acc[st][nt] = (f32x4){0.f, 0.f, 0.f, 0.f};

#pragma unroll
  for (int kc = 0; kc < 4; kc++) {
    bf16x8 x0 = *(const bf16x8*)(X + (size_t)ra0 * D128 + kc * 32 + quad * 8);
    bf16x8 x1 = *(const bf16x8*)(X + (size_t)ra1 * D128 + kc * 32 + quad * 8);
#pragma unroll
    for (int nt = 0; nt < 8; nt++) {
      bf16x8 wf = Wf[(nt * 4 + kc) * 64 + lane];
      acc[0][nt] = __builtin_amdgcn_mfma_f32_16x16x32_bf16(wf, x0, acc[0][nt], 0, 0, 0);
      acc[1][nt] = __builtin_amdgcn_mfma_f32_16x16x32_bf16(wf, x1, acc[1][nt], 0, 0, 0);
    }
  }

  // lane holds channels nt*16+quad*4..+3 for X-row wave*32+st*16+m
#pragma unroll
  for (int st = 0; st < 2; st++)
#pragma unroll
    for (int nt = 0; nt < 8; nt++)
      Ys8[wave * 32 + st * 16 + m][nt * 4 + quad] =
          pack_fp8x4(acc[st][nt][0], acc[st][nt][1], acc[st][nt][2], acc[st][nt][3]);
  __syncthreads();

#pragma unroll
  for (int it = 0; it < 4; it++) {
    int f = tid + 256 * it;        // 0..1023
    int row = f >> 3;
    int cu = (f & 7) * 4;
    int grow = row0 + row;
    if (grow < M) *(uint4*)(P + (size_t)grow * 32 + cu) = *(const uint4*)(&Ys8[row][cu]);
  }
}

// ---------------------------------------------------------------------------
// Fused attention + aggregation, WAVE-PER-DST, TWO-PHASE, fp8 tables.
// Phase 1 (score): 16 lanes/edge, 4 edges/iter; ex -> LDS, den in registers.
// Phase 2 (agg): 32 lanes cover a 128-B fp8 row -> 2 edges per load step,
// 8 independent gathers in flight per lane (16 edges per unrolled iter).
// No block barriers. deg > SCAPW: global-staged slow path.
// ---------------------------------------------------------------------------
__global__ __launch_bounds__(256) void attn_agg_kernel(
    const uint32* __restrict__ p_src_f8, const uint32* __restrict__ p_dst_f8,
    const float* __restrict__ w2, const float* __restrict__ ew,
    const int* __restrict__ src_idx, const int* __restrict__ off,
    const uint32* __restrict__ h_src_f8,
    float* __restrict__ attn_out, uint32* __restrict__ h_glob_bf, int N_dst) {
  const int tid = threadIdx.x;
  const int wv = tid >> 6;
  const int lane = tid & 63;
  const int v = blockIdx.x * 4 + wv;

  __shared__ float sex[4][SCAPW];
  __shared__ int ssrc[4][SCAPW];
  if (v >= N_dst) return;

  const int lo = off[v], hi = off[v + 1];
  const int deg = hi - lo;
  const int sub = lane & 15;   // lane covers channels sub*8..+7 (score)
  const int eg = lane >> 4;    // edge slot 0..3 (score)
  const bool fast = (deg <= SCAPW);

  // per-lane w2 segment + decoded p_dst segment (row wave-uniform, L1-hot)
  float4 wA = *(const float4*)(w2 + sub * 8);
  float4 wB = *(const float4*)(w2 + sub * 8 + 4);
  uint2 pdu = *(const uint2*)(p_dst_f8 + (size_t)v * 32 + sub * 2);
  f32x2 pd0 = __builtin_amdgcn_cvt_pk_f32_fp8(pdu.x, false);
  f32x2 pd1 = __builtin_amdgcn_cvt_pk_f32_fp8(pdu.x, true);
  f32x2 pd2 = __builtin_amdgcn_cvt_pk_f32_fp8(pdu.y, false);
  f32x2 pd3 = __builtin_amdgcn_cvt_pk_f32_fp8(pdu.y, true);

  // ---- phase 1: scores ----
  float den = 0.f;
  for (int base = 0; base < deg; base += 4) {
    const int ei = base + eg;
    float ex = 0.f;
    if (ei < deg) {
      const int e = lo + ei;
      const int s = src_idx[e];
      const float ewv = ew[e];
      uint2 us = *(const uint2*)(p_src_f8 + (size_t)s * 32 + sub * 2);
      f32x2 a0 = __builtin_amdgcn_cvt_pk_f32_fp8(us.x, false);
      f32x2 a1 = __builtin_amdgcn_cvt_pk_f32_fp8(us.x, true);
      f32x2 a2 = __builtin_amdgcn_cvt_pk_f32_fp8(us.y, false);
      f32x2 a3 = __builtin_amdgcn_cvt_pk_f32_fp8(us.y, true);
      float sc;
      sc = fast_tanh(a0.x + pd0.x) * wA.x;
      sc = fmaf(fast_tanh(a0.y + pd0.y), wA.y, sc);
      sc = fmaf(fast_tanh(a1.x + pd1.x), wA.z, sc);
      sc = fmaf(fast_tanh(a1.y + pd1.y), wA.w, sc);
      sc = fmaf(fast_tanh(a2.x + pd2.x), wB.x, sc);
      sc = fmaf(fast_tanh(a2.y + pd2.y), wB.y, sc);
      sc = fmaf(fast_tanh(a3.x + pd3.x), wB.z, sc);
      sc = fmaf(fast_tanh(a3.y + pd3.y), wB.w, sc);
#pragma unroll
      for (int o = 1; o <= 8; o <<= 1) sc += __shfl_xor(sc, o, 64);
      ex = __expf(sc * ewv);
      if (sub == 0) {
        if (fast) { sex[wv][ei] = ex; ssrc[wv][ei] = s; }
        else attn_out[lo + ei] = ex;   // staged un-normalized
      }
    }
    den += (sub == 0) ? ex : 0.f;
  }
#pragma unroll
  for (int o = 1; o <= 32; o <<= 1) den += __shfl_xor(den, o, 64);
  const float inv = (deg > 0) ? 1.0f / den : 0.0f;

  // ---- phase 2: aggregation (32 lanes per fp8 row, 2 edges per step) ----
  const int c4 = lane & 31;    // channel group: channels c4*4..+3
  const int hw = lane >> 5;    // which edge of the pair
  float a0 = 0.f, a1 = 0.f, a2 = 0.f, a3 = 0.f;

  if (fast) {
    const int pad = (deg + 15) & ~15;
    for (int i = deg + lane; i < pad; i += 64) { sex[wv][i] = 0.f; ssrc[wv][i] = 0; }
    for (int i = lane; i < deg; i += 64) attn_out[lo + i] = sex[wv][i] * inv;
    for (int b = 0; b < pad; b += 16) {
#pragma unroll
      for (int j = 0; j < 8; j++) {
        const int idx = b + j * 2 + hw;
        float ex = sex[wv][idx];
        int s = ssrc[wv][idx];
        uint32 u = h_src_f8[(size_t)s * 32 + c4];
        f32x2 h0 = __builtin_amdgcn_cvt_pk_f32_fp8(u, false);
        f32x2 h1 = __builtin_amdgcn_cvt_pk_f32_fp8(u, true);
        a0 = fmaf(ex, h0.x, a0);
        a1 = fmaf(ex, h0.y, a1);
        a2 = fmaf(ex, h1.x, a2);
        a3 = fmaf(ex, h1.y, a3);
      }
    }
  } else {
    for (int b = 0; b < deg; b += 16) {
#pragma unroll
      for (int j = 0; j < 8; j++) {
        const int idx = b + j * 2 + hw;
        float ex = 0.f;
        int s = 0;
        if (idx < deg) { ex = attn_out[lo + idx]; s = src_idx[lo + idx]; }
        uint32 u = h_src_f8[(size_t)s * 32 + c4];
        f32x2 h0 = __builtin_amdgcn_cvt_pk_f32_fp8(u, false);
        f32x2 h1 = __builtin_amdgcn_cvt_pk_f32_fp8(u, true);
        a0 = fmaf(ex, h0.x, a0);
        a1 = fmaf(ex, h0.y, a1);
        a2 = fmaf(ex, h1.x, a2);
        a3 = fmaf(ex, h1.y, a3);
      }
    }
    // normalize attn AFTER all reads (same wave, sequential)
    for (int i = lane; i < deg; i += 64) attn_out[lo + i] *= inv;
  }

  // reduce the 2 edge-halves (lanes differ in bit 5)
  a0 += __shfl_xor(a0, 32, 64);
  a1 += __shfl_xor(a1, 32, 64);
  a2 += __shfl_xor(a2, 32, 64);
  a3 += __shfl_xor(a3, 32, 64);
  if (hw == 0) {   // lanes 0..31 hold channels c4*4..+3
    uint2 o;
    o.x = pack_bf2(a0 * inv, a1 * inv);
    o.y = pack_bf2(a2 * inv, a3 * inv);
    *(uint2*)(h_glob_bf + (size_t)v * 64 + c4 * 2) = o;
  }
}

// ---------------------------------------------------------------------------
// MFMA output projection + fused LayerNorm.
// ---------------------------------------------------------------------------
__global__ __launch_bounds__(128) void out_mfma_ln(
    const ushort_t* __restrict__ h_dst_bf, const ushort_t* __restrict__ h_glob_bf,
    const ushort_t* __restrict__ Wo_frag,
    const float* __restrict__ h_dst, const float* __restrict__ bo,
    const float* __restrict__ gamma, const float* __restrict__ beta,
    float* __restrict__ y, int N) {
  __shared__ float sbo[128], sgam[128], sbet[128];
  const int tid = threadIdx.x;
  if (tid < 128) { sbo[tid] = bo[tid]; sgam[tid] = gamma[tid]; sbet[tid] = beta[tid]; }
  __syncthreads();

  const int w = tid >> 6;
  const int lane = tid & 63;
  const int m = lane & 15;
  const int quad = lane >> 4;
  const int row0 = blockIdx.x * 32 + w * 16;
  const int ra = min(row0 + m, N - 1);
  const bf16x8* Wf = (const bf16x8*)Wo_frag;

  f32x4 acc[8];
#pragma unroll
  for (int nt = 0; nt < 8; nt++) acc[nt] = (f32x4){0.f, 0.f, 0.f, 0.f};

#pragma unroll
  for (int kc = 0; kc < 8; kc++) {
    const ushort_t* X = (kc < 4) ? h_dst_bf : h_glob_bf;
    const int kk = kc & 3;
    bf16x8 a = *(const bf16x8*)(X + (size_t)ra * D128 + kk * 32 + quad * 8);
#pragma unroll
    for (int nt = 0; nt < 8; nt++) {
      bf16x8 bfr = Wf[(nt * 8 + kc) * 64 + lane];
      acc[nt] = __builtin_amdgcn_mfma_f32_16x16x32_bf16(a, bfr, acc[nt], 0, 0, 0);
    }
  }

#pragma unroll
  for (int r = 0; r < 4; r++) {
    const int grow = row0 + quad * 4 + r;
    const int gr = min(grow, N - 1);
    float x[8];
    float s1 = 0.f, s2 = 0.f;
#pragma unroll
    for (int nt = 0; nt < 8; nt++) {
      float hd = h_dst[(size_t)gr * D128 + nt * 16 + m];
      float xv = hd + acc[nt][r] + sbo[nt * 16 + m];
      x[nt] = xv;
      s1 += xv;
      s2 = fmaf(xv, xv, s2);
    }
#pragma unroll
    for (int o = 1; o <= 8; o <<= 1) {
      s1 += __shfl_xor(s1, o, 64);
      s2 += __shfl_xor(s2, o, 64);
    }
    float mu = s1 * (1.0f / 128.0f);
    float var = s2 * (1.0f / 128.0f) - mu * mu;
    float rstd = __builtin_amdgcn_rcpf(sqrtf(var + 1e-5f));
    if (grow < N) {
#pragma unroll
      for (int nt = 0; nt < 8; nt++) {
        int c = nt * 16 + m;
        y[(size_t)grow * D128 + c] = (x[nt] - mu) * rstd * sgam[c] + sbet[c];
      }
    }
  }
}

extern "C" void kernel_launch(void* const* d_in, const int* in_sizes, int n_in,
                              void* d_out, int out_size, void* d_ws, size_t ws_size,
                              hipStream_t stream) {
  const float* h_src = (const float*)d_in[0];
  const float* h_dst = (const float*)d_in[1];
  const float* s_emb = (const float*)d_in[2];
  const float* ew    = (const float*)d_in[3];
  const int* src_idx = (const int*)d_in[4];
  const int* dst_idx = (const int*)d_in[5];
  const float* W1    = (const float*)d_in[6];
  const float* w2    = (const float*)d_in[7];
  const float* Wo    = (const float*)d_in[8];
  const float* bo    = (const float*)d_in[9];
  const float* gamma = (const float*)d_in[10];
  const float* beta  = (const float*)d_in[11];

  const int N_src = in_sizes[0] / D128;
  const int N_dst = in_sizes[1] / D128;
  const int E = in_sizes[3];

  float* out_y = (float*)d_out;                       // [N_dst*128]
  float* out_attn = out_y + (size_t)N_dst * D128;     // [E]

  // ws layout:
  uint32* p_src_f8 = (uint32*)d_ws;                            // N_src*32 (fp8 rows)
  uint32* p_dst_f8 = p_src_f8 + (size_t)N_src * 32;            // N_dst*32
  uint32* h_src_f8 = p_dst_f8 + (size_t)N_dst * 32;            // N_src*32
  uint32* h_src_bf = h_src_f8 + (size_t)N_src * 32;            // N_src*64 (bf16)
  uint32* h_dst_bf = h_src_bf + (size_t)N_src * 64;            // N_dst*64
  uint32* h_glob_bf = h_dst_bf + (size_t)N_dst * 64;           // N_dst*64
  uint32* s_emb_bf = h_glob_bf + (size_t)N_dst * 64;           // N_dst*64
  int* seg_off = (int*)(s_emb_bf + (size_t)N_dst * 64);        // N_dst+1
  ushort_t* Wfrag = (ushort_t*)(seg_off + N_dst + 1 + 3);      // 32768 shorts
  ushort_t* Wo_frag = Wfrag + 32768;                           // 32768 shorts

  const int n_src_el = N_src * D128;
  const int n_dst_el = N_dst * D128;
  const int n_conv_el = n_src_el + 2 * n_dst_el;   // h_src once (dual write) + s_emb + h_dst
  const int nblk_a = (N_src + 127) / 128;
  const int nblk_b = (N_dst + 127) / 128;
  const int nb_conv = (n_conv_el / 8 + 255) / 256;
  const int nb_seg = (E + 255) / 256;

  prep_all<<<nb_conv + 32 + nb_seg, 256, 0, stream>>>(
      h_src, s_emb, h_dst, W1, Wo, dst_idx,
      h_src_bf, s_emb_bf, h_dst_bf, h_src_f8, Wfrag, Wo_frag, seg_off,
      n_src_el, n_dst_el, E, N_dst, nb_conv);
  gemm_mfma<<<nblk_a + nblk_b, 256, 0, stream>>>(
      (const ushort_t*)h_src_bf, (const ushort_t*)s_emb_bf, Wfrag,
      p_src_f8, p_dst_f8, N_src, N_dst, nblk_a);
  attn_agg_kernel<<<(N_dst + 3) / 4, 256, 0, stream>>>(
      p_src_f8, p_dst_f8, w2, ew, src_idx, seg_off, h_src_f8, out_attn,
      h_glob_bf, N_dst);
  out_mfma_ln<<<(N_dst + 31) / 32, 128, 0, stream>>>(
      (const ushort_t*)h_dst_bf, (const ushort_t*)h_glob_bf, Wo_frag,
      h_dst, bo, gamma, beta, out_y, N_dst);
}